// Round 1
// baseline (553.957 us; speedup 1.0000x reference)
//
#include <hip/hip_runtime.h>

// Problem constants (from reference setup_inputs)
constexpr int B  = 32;
constexpr int H  = 224;
constexpr int W  = 224;
constexpr int C  = 64;
constexpr int OH = 112;   // ceil(224/2)
constexpr int OW = 112;
constexpr int C4 = C / 4; // 16 float4 groups per pixel

__global__ __launch_bounds__(256)
void gradpool_kernel(const float* __restrict__ x,
                     const float* __restrict__ lamb_p,
                     float* __restrict__ out)
{
    long long idx = (long long)blockIdx.x * blockDim.x + threadIdx.x;
    const long long total = (long long)B * OH * OW * C4;
    if (idx >= total) return;

    const int c4 = (int)(idx & (C4 - 1));
    long long t = idx >> 4;          // / C4
    const int oj = (int)(t % OW); t /= OW;
    const int oi = (int)(t % OH);
    const int b  = (int)(t / OH);

    const float lamb = *lamb_p;

    const float* xb = x + (long long)b * H * W * C + (long long)c4 * 4;

    auto ld = [&](int r, int w) -> float4 {
        return *(const float4*)(xb + ((long long)r * W + w) * C);
    };

    const int r1 = 2 * oi;
    const int w1 = 2 * oj;

    // 2x2 pooling window in x coords: rows {r1-1, r1}, cols {w1-1, w1};
    // -1 means zero padding (jnp.pad with 0), which participates in BOTH
    // the max (init -inf, pad=0) and the sum.
    const float4 z = make_float4(0.f, 0.f, 0.f, 0.f);
    float4 v11 = ld(r1, w1);
    float4 v01 = (oi > 0)           ? ld(r1 - 1, w1)     : z;
    float4 v10 = (oj > 0)           ? ld(r1, w1 - 1)     : z;
    float4 v00 = (oi > 0 && oj > 0) ? ld(r1 - 1, w1 - 1) : z;

    // Selector taps (unstrided coords — quirk of the reference slicing).
    // All indices in [0,113) — always valid, no padding involved.
    float4 a = ld(oi + 1, oj + 1);
    float4 u = ld(oi,     oj + 1);
    float4 l = ld(oi + 1, oj);

    const float* e00 = (const float*)&v00;
    const float* e01 = (const float*)&v01;
    const float* e10 = (const float*)&v10;
    const float* e11 = (const float*)&v11;
    const float* ea  = (const float*)&a;
    const float* eu  = (const float*)&u;
    const float* el  = (const float*)&l;

    float4 res;
    float* rp = (float*)&res;
    #pragma unroll
    for (int k = 0; k < 4; ++k) {
        float mx = fmaxf(fmaxf(e00[k], e01[k]), fmaxf(e10[k], e11[k]));
        float mn = (e00[k] + e01[k] + e10[k] + e11[k]) * 0.25f;
        float d  = 2.0f * (fabsf(ea[k] - eu[k]) + fabsf(ea[k] - el[k]));
        rp[k] = (d > lamb) ? mx : mn;
    }

    float* op = out + (((long long)b * OH + oi) * OW + oj) * C + (long long)c4 * 4;
    *(float4*)op = res;
}

extern "C" void kernel_launch(void* const* d_in, const int* in_sizes, int n_in,
                              void* d_out, int out_size, void* d_ws, size_t ws_size,
                              hipStream_t stream)
{
    const float* x    = (const float*)d_in[0];
    const float* lamb = (const float*)d_in[1];
    float* out        = (float*)d_out;

    const long long total = (long long)B * OH * OW * C4; // 6,422,528
    const int block = 256;
    const int grid  = (int)((total + block - 1) / block); // 25,088

    gradpool_kernel<<<grid, block, 0, stream>>>(x, lamb, out);
}